// Round 1
// baseline (563.444 us; speedup 1.0000x reference)
//
#include <hip/hip_runtime.h>
#include <hip/hip_bf16.h>
#include <stdint.h>

// Problem: out = ReLU((din*mask + bias*mask) @ W), din [8192,4096] fp32 ~10% dense,
// W [4096,4096] fp32 row-major (j = rows = K dim), bias [4096].
// Strategy: cast to bf16, NT-layout MFMA GEMM (m97 structure: 128x128 tile, BK=32,
// global_load_lds width 16, 16x16x32 bf16 MFMA, 4 waves x 4x4 acc tiles).

#define M_ROWS 8192
#define N_COLS 4096
#define K_DIM  4096

#define BM 128
#define BN 128
#define BK 32

typedef __bf16 bf16x8_t __attribute__((ext_vector_type(8)));
typedef float f32x4_t __attribute__((ext_vector_type(4)));

__device__ __forceinline__ void gload_lds16(const void* gsrc, void* ldst) {
  // 16B per lane, LDS dest = wave-uniform base + lane*16 (hardware rule).
  __builtin_amdgcn_global_load_lds(
      (const __attribute__((address_space(1))) uint32_t*)gsrc,
      (__attribute__((address_space(3))) uint32_t*)ldst,
      16, 0, 0);
}

__device__ __forceinline__ ushort f32_to_bf16(float f) {
  uint32_t u = __builtin_bit_cast(uint32_t, f);
  // round-to-nearest-even (NaN irrelevant for this data)
  uint32_t r = (u + 0x7fffu + ((u >> 16) & 1u)) >> 16;
  return (ushort)r;
}

// A_bf16[b,j] = din[b,j] != 0 ? bf16(din[b,j] + bias[j]) : 0
__global__ __launch_bounds__(256)
void prep_a(const float* __restrict__ din, const float* __restrict__ bias,
            ushort* __restrict__ Abf) {
  int64_t i4 = (int64_t)blockIdx.x * 256 + threadIdx.x;  // one float4 per thread
  float4 d = ((const float4*)din)[i4];
  int j4 = (int)(i4 & (K_DIM / 4 - 1));
  float4 bv = ((const float4*)bias)[j4];
  ushort4 o;
  o.x = f32_to_bf16(d.x != 0.f ? d.x + bv.x : 0.f);
  o.y = f32_to_bf16(d.y != 0.f ? d.y + bv.y : 0.f);
  o.z = f32_to_bf16(d.z != 0.f ? d.z + bv.z : 0.f);
  o.w = f32_to_bf16(d.w != 0.f ? d.w + bv.w : 0.f);
  ((ushort4*)Abf)[i4] = o;
}

// Wt_bf16[n, j] = bf16(W[j, n])  -- makes GEMM B-operand K-contiguous (NT layout)
__global__ __launch_bounds__(256)
void transpose_w(const float* __restrict__ W, ushort* __restrict__ Wt) {
  __shared__ float tile[32][33];  // +1 pad: conflict-free transposed read
  const int tx = threadIdx.x;  // 0..31
  const int ty = threadIdx.y;  // 0..7
  const int n0 = blockIdx.x * 32;
  const int j0 = blockIdx.y * 32;
#pragma unroll
  for (int i = 0; i < 32; i += 8)
    tile[ty + i][tx] = W[(int64_t)(j0 + ty + i) * K_DIM + (n0 + tx)];
  __syncthreads();
#pragma unroll
  for (int i = 0; i < 32; i += 8)
    Wt[(int64_t)(n0 + ty + i) * K_DIM + (j0 + tx)] = f32_to_bf16(tile[tx][ty + i]);
}

// C[M,N] = relu(A[M,K] * Bt[N,K]^T), bf16 in / fp32 out.
// Block: 256 threads = 4 waves (2x2), each wave a 64x64 sub-tile = 4x4 MFMA tiles.
__global__ __launch_bounds__(256, 3)
void gemm_bt_relu(const ushort* __restrict__ A, const ushort* __restrict__ Bt,
                  float* __restrict__ C) {
  __shared__ __align__(16) ushort As[BM * BK];  // 8 KB, row-major [128][32], NO pad
  __shared__ __align__(16) ushort Bs[BN * BK];  // (global_load_lds lane-order layout)

  const int tid = threadIdx.x;
  const int wave = tid >> 6;
  const int lane = tid & 63;
  const int wm = wave >> 1;
  const int wn = wave & 1;
  const int quad = lane >> 4;
  const int l16 = lane & 15;

  const int bm = blockIdx.y;
  const int bn = blockIdx.x;

  // Staging: chunk c covers rows [c*16, c*16+16); lane l -> row c*16 + l/4,
  // 16B piece (l%4) within the 64B row. LDS byte = c*1024 + l*16 (matches HW rule).
  const int lrow = lane >> 2;
  const int lcol = lane & 3;
  const int c0 = wave * 2 + 0;
  const int c1 = wave * 2 + 1;

  const char* aSrc0 = (const char*)A + (((int64_t)(bm * BM + c0 * 16 + lrow) * K_DIM) + lcol * 8) * 2;
  const char* aSrc1 = (const char*)A + (((int64_t)(bm * BM + c1 * 16 + lrow) * K_DIM) + lcol * 8) * 2;
  const char* bSrc0 = (const char*)Bt + (((int64_t)(bn * BN + c0 * 16 + lrow) * K_DIM) + lcol * 8) * 2;
  const char* bSrc1 = (const char*)Bt + (((int64_t)(bn * BN + c1 * 16 + lrow) * K_DIM) + lcol * 8) * 2;

  ushort* aDst0 = As + c0 * 512;
  ushort* aDst1 = As + c1 * 512;
  ushort* bDst0 = Bs + c0 * 512;
  ushort* bDst1 = Bs + c1 * 512;

  f32x4_t acc[4][4];
#pragma unroll
  for (int i = 0; i < 4; ++i)
#pragma unroll
    for (int j = 0; j < 4; ++j)
      acc[i][j] = (f32x4_t){0.f, 0.f, 0.f, 0.f};

  const int arow = wm * 64 + l16;  // A-frag m index: m = lane&15 (verified layout)
  const int brow = wn * 64 + l16;  // B-frag n index

  for (int kt = 0; kt < K_DIM / BK; ++kt) {
    __syncthreads();  // previous iteration's ds_reads done before overwrite
    gload_lds16(aSrc0, aDst0);
    gload_lds16(aSrc1, aDst1);
    gload_lds16(bSrc0, bDst0);
    gload_lds16(bSrc1, bDst1);
    aSrc0 += BK * 2; aSrc1 += BK * 2; bSrc0 += BK * 2; bSrc1 += BK * 2;
    __syncthreads();  // vmcnt(0) drained before barrier -> tiles visible

    bf16x8_t af[4], bfr[4];
#pragma unroll
    for (int t = 0; t < 4; ++t) {
      af[t]  = *(const bf16x8_t*)(As + (arow + t * 16) * BK + quad * 8);
      bfr[t] = *(const bf16x8_t*)(Bs + (brow + t * 16) * BK + quad * 8);
    }
#pragma unroll
    for (int tm = 0; tm < 4; ++tm)
#pragma unroll
      for (int tn = 0; tn < 4; ++tn)
        acc[tm][tn] = __builtin_amdgcn_mfma_f32_16x16x32_bf16(af[tm], bfr[tn], acc[tm][tn], 0, 0, 0);
  }

  // Epilogue: C/D layout col=lane&15, row=quad*4+reg (verified m89/m91). ReLU fused.
#pragma unroll
  for (int tm = 0; tm < 4; ++tm) {
#pragma unroll
    for (int tn = 0; tn < 4; ++tn) {
      const int col = bn * BN + wn * 64 + tn * 16 + l16;
      const int row0 = bm * BM + wm * 64 + tm * 16 + quad * 4;
#pragma unroll
      for (int i = 0; i < 4; ++i) {
        float v = acc[tm][tn][i];
        C[(int64_t)(row0 + i) * N_COLS + col] = v > 0.f ? v : 0.f;
      }
    }
  }
}

extern "C" void kernel_launch(void* const* d_in, const int* in_sizes, int n_in,
                              void* d_out, int out_size, void* d_ws, size_t ws_size,
                              hipStream_t stream) {
  const float* din = (const float*)d_in[0];     // [8192, 4096] fp32
  const float* weight = (const float*)d_in[1];  // [4096, 4096] fp32
  const float* bias = (const float*)d_in[2];    // [4096] fp32
  float* out = (float*)d_out;                   // [8192, 4096] fp32

  // Workspace: A_bf16 (67.1 MB) then Wt_bf16 (33.6 MB) = 100.7 MB total.
  ushort* Abf = (ushort*)d_ws;
  ushort* Wt = (ushort*)((char*)d_ws + (size_t)M_ROWS * K_DIM * 2);

  prep_a<<<(M_ROWS * K_DIM / 4) / 256, 256, 0, stream>>>(din, bias, Abf);
  transpose_w<<<dim3(K_DIM / 32, K_DIM / 32), dim3(32, 8), 0, stream>>>(weight, Wt);
  gemm_bt_relu<<<dim3(N_COLS / BN, M_ROWS / BM), 256, 0, stream>>>(Abf, Wt, out);
}